// Round 3
// 187.995 us; speedup vs baseline: 1.0024x; 1.0024x over previous
//
#include <hip/hip_runtime.h>
#include <cstdint>
#include <cstddef>

#define N 4096
#define M 4096
#define DT 0.01f

#define BM 128
#define BN 256
#define BK 64   // K elements per tile (2 MFMA phases of K=32)

#define ABYTES 16384      // 128 x 64 bf16
#define BBYTES 32768      // 256 x 64 bf16
#define BUFBYTES 49152    // A + B per buffer

typedef short bf16x8 __attribute__((ext_vector_type(8)));
typedef float f32x4 __attribute__((ext_vector_type(4)));

__device__ __forceinline__ unsigned short f2bf(float f) {
  unsigned u = __builtin_bit_cast(unsigned, f);
  return (unsigned short)((u + 0x7fffu + ((u >> 16) & 1u)) >> 16);  // RNE
}

// Fused prep. Blocks [0,4096): exp-transpose tiles -> kbT[i*N+l]=bf16(exp(-x[l*M+i])).
// Blocks [4096,8192): weighted Toeplitz row j: Tm[j*N+l] = w*h[j-l] (l<=j else 0),
// w = 1 + 0.5*[l==j] - 0.5*[l==0]   =>   out = fe[j] - dt*(Tm @ k)[j,i].
__global__ __launch_bounds__(256)
void prep_kernel(const float* __restrict__ x, const float* __restrict__ h,
                 unsigned short* __restrict__ kbT, unsigned short* __restrict__ Tm) {
  __shared__ __align__(16) unsigned short smem[64 * 66];  // 8448 B, both modes
  const int bid = (int)blockIdx.x;
  const int tid = threadIdx.x;

  if (bid < 4096) {
    // ---- exp-transpose 64x64 tile ----
    unsigned short (*tileT)[66] = (unsigned short(*)[66])smem;  // [i][l]
    const int i0 = (bid & 63) * 64, l0 = (bid >> 6) * 64;
    const int ci = (tid & 15) * 4;
    const int r0 = tid >> 4;
#pragma unroll
    for (int rr = 0; rr < 4; ++rr) {
      const int l = l0 + r0 + rr * 16;
      const float4 xv = *reinterpret_cast<const float4*>(&x[(size_t)l * M + i0 + ci]);
      const int lr = r0 + rr * 16;
      tileT[ci + 0][lr] = f2bf(__expf(-xv.x));
      tileT[ci + 1][lr] = f2bf(__expf(-xv.y));
      tileT[ci + 2][lr] = f2bf(__expf(-xv.z));
      tileT[ci + 3][lr] = f2bf(__expf(-xv.w));
    }
    __syncthreads();
    const int ir = tid >> 2, cc = tid & 3;
#pragma unroll
    for (int s = 0; s < 2; ++s) {
      const int ch = cc + s * 4;
      bf16x8 v = *reinterpret_cast<const bf16x8*>(&tileT[ir][ch * 8]);
      *reinterpret_cast<bf16x8*>(&kbT[(size_t)(i0 + ir) * N + l0 + ch * 8]) = v;
    }
  } else {
    // ---- Toeplitz row j ----
    const int j = bid - 4096;
    unsigned short* hb = smem;  // hb[0..4095] = bf16(h[.])
#pragma unroll
    for (int p = 0; p < 4; ++p) {
      const int idx = p * 1024 + tid * 4;
      const float4 hv = *reinterpret_cast<const float4*>(&h[idx]);
      ushort4 pk;
      pk.x = f2bf(hv.x); pk.y = f2bf(hv.y); pk.z = f2bf(hv.z); pk.w = f2bf(hv.w);
      *reinterpret_cast<ushort4*>(&hb[idx]) = pk;
    }
    __syncthreads();
    const int l0 = tid * 16;
    unsigned short v[16];
#pragma unroll
    for (int s = 0; s < 16; ++s) {
      const int l = l0 + s;
      unsigned short r = 0;
      if (l <= j) {
        const float w = 1.0f + (l == j ? 0.5f : 0.0f) - (l == 0 ? 0.5f : 0.0f);
        float hv = __builtin_bit_cast(float, (unsigned)hb[j - l] << 16);
        r = f2bf(w * hv);
      }
      v[s] = r;
    }
#pragma unroll
    for (int half = 0; half < 2; ++half) {
      uint4 pk;
      const unsigned short* q = &v[half * 8];
      pk.x = (unsigned)q[0] | ((unsigned)q[1] << 16);
      pk.y = (unsigned)q[2] | ((unsigned)q[3] << 16);
      pk.z = (unsigned)q[4] | ((unsigned)q[5] << 16);
      pk.w = (unsigned)q[6] | ((unsigned)q[7] << 16);
      *reinterpret_cast<uint4*>(&Tm[(size_t)j * N + l0 + half * 8]) = pk;
    }
  }
}

__device__ __forceinline__ void gld16(void* lds, const void* g) {
  __builtin_amdgcn_global_load_lds(
      (const __attribute__((address_space(1))) void*)g,
      (__attribute__((address_space(3))) void*)lds, 16, 0, 0);
}

// Paired triangular GEMM, 8-phase-style schedule (T2+T3+T4+T5):
//  - 128x256 block tile, 8 waves (2x4), wave tile 64x64.
//  - Triple-buffered LDS (3 x 48 KB = 144 KB), prefetch depth 2: stage(t+2)
//    issued during tile t's compute -> tile-boundary wait is vmcnt(6)
//    (tile t+1 landed, tile t+2's 6 loads stay in flight across s_barrier).
//  - Per K-tile (BK=64): 2 phases, each {8 ds_read_b128 | 3 gld16 ->
//    s_barrier -> lgkmcnt(0) -> setprio(1) -> 16 MFMA -> setprio(0) -> s_barrier}.
//  - XOR chunk swizzle unchanged (pre-swizzled global src, linear LDS dest,
//    swizzled reads); bank conflicts stay ~0.
// Grid 16x16 paired (p, 31-p): every block runs exactly 68 K-tiles -> balanced,
// 1 block/CU, 2 waves/SIMD.
__global__ __launch_bounds__(512)
void gemm_tri_kernel(const unsigned short* __restrict__ Tm,
                     const unsigned short* __restrict__ Bt,
                     const float* __restrict__ fe,
                     float* __restrict__ out) {
  __shared__ __align__(16) char sm[3 * BUFBYTES];  // 144 KB

  const int tid = threadIdx.x;
  const int wave = tid >> 6, lane = tid & 63;
  const int wr = wave >> 2, wc = wave & 3;       // 2 x 4 wave grid
  const int lo16 = lane & 15, hi4 = lane >> 4;
  const int i0 = blockIdx.x * BN;
  const int p = (int)blockIdx.y;
  const int sw = lo16 & 7;  // read swizzle key (== row&7 for this lane's rows)

  const size_t strideB = (size_t)N * 2;  // 8192 B per matrix row

  // staging: pass pp covers rows pp*64 .. pp*64+63; chunk c = pp*512 + tid;
  // row = c>>3, phys chunk = c&7, global chunk = (c&7) ^ (row&7)
  const int srow = tid >> 3;                       // row within a 64-row pass
  const int gq = ((tid & 7) ^ (srow & 7)) * 16;    // pre-swizzled global chunk

  // one 64-row pass (512 chunks of 16 B) of A into buffer buf; ppA in {0,1}
  auto stageA = [&](int j0s, int t, int buf, int pp) {
    const char* Abase = (const char*)Tm + (size_t)j0s * strideB + (size_t)t * 128;
    gld16(sm + buf * BUFBYTES + pp * 8192 + wave * 1024,
          Abase + (size_t)(srow + pp * 64) * strideB + gq);
  };
  // one 64-row pass of B; ppB in {0,1,2,3}
  auto stageB = [&](int t, int buf, int pp) {
    const char* Bbase = (const char*)Bt + (size_t)i0 * strideB + (size_t)t * 128;
    gld16(sm + buf * BUFBYTES + ABYTES + pp * 8192 + wave * 1024,
          Bbase + (size_t)(srow + pp * 64) * strideB + gq);
  };

#pragma unroll 1
  for (int ph = 0; ph < 2; ++ph) {
    const int by = ph ? (31 - p) : p;
    const int j0 = by * BM;
    const int nIter = 2 * by + 2;  // causal bound: K <= 128*(by+1)

    f32x4 acc[4][4] = {};

    // prologue: stage tiles 0 and 1 (12 gld16 in flight)
    stageA(j0, 0, 0, 0); stageA(j0, 0, 0, 1);
    stageB(0, 0, 0); stageB(0, 0, 1); stageB(0, 0, 2); stageB(0, 0, 3);
    stageA(j0, 1, 1, 0); stageA(j0, 1, 1, 1);
    stageB(1, 1, 0); stageB(1, 1, 1); stageB(1, 1, 2); stageB(1, 1, 3);
    asm volatile("s_waitcnt vmcnt(6)" ::: "memory");  // tile 0 landed; tile 1 in flight
    __builtin_amdgcn_s_barrier();

    int cur = 0;
#pragma unroll 1
    for (int t = 0; t < nIter; ++t) {
      const char* AsC = sm + cur * BUFBYTES;
      const char* BsC = AsC + ABYTES;
      const int nxt = (cur == 0) ? 2 : cur - 1;   // (cur+2)%3
      const bool doStage = (t + 2 < nIter);

      // ================= phase 0 (K-half h2=0) =================
      {
        bf16x8 af[4], bfr[4];
        const int q = hi4 ^ sw;
#pragma unroll
        for (int mt = 0; mt < 4; ++mt) {
          const int row = wr * 64 + mt * 16 + lo16;
          af[mt] = *reinterpret_cast<const bf16x8*>(AsC + row * 128 + q * 16);
        }
#pragma unroll
        for (int nt = 0; nt < 4; ++nt) {
          const int row = wc * 64 + nt * 16 + lo16;
          bfr[nt] = *reinterpret_cast<const bf16x8*>(BsC + row * 128 + q * 16);
        }
        if (doStage) {
          stageA(j0, t + 2, nxt, 0);
          stageB(t + 2, nxt, 0);
          stageB(t + 2, nxt, 1);
        }
        __builtin_amdgcn_s_barrier();
        asm volatile("s_waitcnt lgkmcnt(0)" ::: "memory");
        __builtin_amdgcn_s_setprio(1);
#pragma unroll
        for (int mt = 0; mt < 4; ++mt)
#pragma unroll
          for (int nt = 0; nt < 4; ++nt)
            acc[mt][nt] = __builtin_amdgcn_mfma_f32_16x16x32_bf16(
                af[mt], bfr[nt], acc[mt][nt], 0, 0, 0);
        __builtin_amdgcn_s_setprio(0);
        __builtin_amdgcn_s_barrier();
      }

      // ================= phase 1 (K-half h2=1) =================
      {
        bf16x8 af[4], bfr[4];
        const int q = (4 + hi4) ^ sw;
#pragma unroll
        for (int mt = 0; mt < 4; ++mt) {
          const int row = wr * 64 + mt * 16 + lo16;
          af[mt] = *reinterpret_cast<const bf16x8*>(AsC + row * 128 + q * 16);
        }
#pragma unroll
        for (int nt = 0; nt < 4; ++nt) {
          const int row = wc * 64 + nt * 16 + lo16;
          bfr[nt] = *reinterpret_cast<const bf16x8*>(BsC + row * 128 + q * 16);
        }
        if (doStage) {
          stageA(j0, t + 2, nxt, 1);
          stageB(t + 2, nxt, 2);
          stageB(t + 2, nxt, 3);
        }
        __builtin_amdgcn_s_barrier();
        asm volatile("s_waitcnt lgkmcnt(0)" ::: "memory");
        __builtin_amdgcn_s_setprio(1);
#pragma unroll
        for (int mt = 0; mt < 4; ++mt)
#pragma unroll
          for (int nt = 0; nt < 4; ++nt)
            acc[mt][nt] = __builtin_amdgcn_mfma_f32_16x16x32_bf16(
                af[mt], bfr[nt], acc[mt][nt], 0, 0, 0);
        __builtin_amdgcn_s_setprio(0);
        // tile boundary: wait tile t+1's 6 loads (leave t+2's 6 in flight);
        // if no t+2 was staged, drain fully so tile t+1 is safe.
        if (doStage) {
          asm volatile("s_waitcnt vmcnt(6)" ::: "memory");
        } else {
          asm volatile("s_waitcnt vmcnt(0)" ::: "memory");
        }
        __builtin_amdgcn_s_barrier();
      }

      cur = (cur == 2) ? 0 : cur + 1;
    }

    // Epilogue: plain stores, out = fe[j] - DT*acc.
#pragma unroll
    for (int mt = 0; mt < 4; ++mt) {
      const int jb = j0 + wr * 64 + mt * 16 + hi4 * 4;
      const float4 fev = *reinterpret_cast<const float4*>(&fe[jb]);
      const float fes[4] = {fev.x, fev.y, fev.z, fev.w};
#pragma unroll
      for (int nt = 0; nt < 4; ++nt) {
        const int i = i0 + wc * 64 + nt * 16 + lo16;
#pragma unroll
        for (int r = 0; r < 4; ++r) {
          out[(size_t)(jb + r) * M + i] = fmaf(-DT, acc[mt][nt][r], fes[r]);
        }
      }
    }
  }
}

extern "C" void kernel_launch(void* const* d_in, const int* in_sizes, int n_in,
                              void* d_out, int out_size, void* d_ws, size_t ws_size,
                              hipStream_t stream) {
  const float* x  = (const float*)d_in[0];
  const float* fe = (const float*)d_in[1];
  const float* h  = (const float*)d_in[2];
  float* out = (float*)d_out;

  const size_t matBytes = (size_t)N * N * sizeof(unsigned short);  // 32 MiB
  if (ws_size < 2 * matBytes) return;

  unsigned short* kbT = (unsigned short*)d_ws;
  unsigned short* Tm  = (unsigned short*)((char*)d_ws + matBytes);

  prep_kernel<<<8192, 256, 0, stream>>>(x, h, kbT, Tm);
  gemm_tri_kernel<<<dim3(M / BN, 16), 512, 0, stream>>>(Tm, kbT, fe, out);
}